// Round 5
// baseline (280.941 us; speedup 1.0000x reference)
//
#include <hip/hip_runtime.h>
#include <hip/hip_bf16.h>

// Sparse MoE: T=2048, D=1024, E=8 routed (H=768, top-2) + shared GatedMLP (1536 hidden)
// decomposed into 2 pseudo-experts of routed shape -> 10 uniform experts.
// R5: fc1 M128xN64xBK64 (32 MFMA/barrier, ~864 blocks); fc2 M128xN64xBK128
// (32 MFMA/barrier, 1152 blocks); gate does atomic routing (no k_sort); 4 kernels.

typedef short bf16x8 __attribute__((ext_vector_type(8)));
typedef float f32x4 __attribute__((ext_vector_type(4)));

__device__ __forceinline__ unsigned short f2b(float f) {
    __hip_bfloat16 h = __float2bfloat16(f);
    return *reinterpret_cast<unsigned short*>(&h);
}

__device__ __forceinline__ void ldst16(const unsigned short* g, unsigned short* l) {
    __builtin_amdgcn_global_load_lds(
        (const __attribute__((address_space(1))) unsigned int*)g,
        (__attribute__((address_space(3))) unsigned int*)l, 16, 0, 0);
}

__device__ __forceinline__ void cvt8(const float* s, unsigned short* d, int j) {
    const float4* sp = reinterpret_cast<const float4*>(s) + (size_t)j * 2;
    float4 v0 = sp[0], v1 = sp[1];
    union { unsigned short u[8]; uint4 v; } o;
    o.u[0]=f2b(v0.x); o.u[1]=f2b(v0.y); o.u[2]=f2b(v0.z); o.u[3]=f2b(v0.w);
    o.u[4]=f2b(v1.x); o.u[5]=f2b(v1.y); o.u[6]=f2b(v1.z); o.u[7]=f2b(v1.w);
    *(reinterpret_cast<uint4*>(d) + j) = o.v;
}

// ---------------- weight conversion fp32->bf16 (+ zero routing counters) -------------
__global__ __launch_bounds__(256) void k_conv(const float* __restrict__ W1,
                                              const float* __restrict__ Ws1,
                                              const float* __restrict__ W2,
                                              const float* __restrict__ Ws2,
                                              unsigned short* __restrict__ W1b,
                                              unsigned short* __restrict__ Ws1b,
                                              unsigned short* __restrict__ W2b,
                                              unsigned short* __restrict__ Ws2b,
                                              int* __restrict__ cnt) {
    if (blockIdx.x == 0 && threadIdx.x < 16) cnt[threadIdx.x] = 0;
    int i = blockIdx.x * 256 + threadIdx.x;
    if (i < 1572864)       cvt8(W1,  W1b,  i);
    else if (i < 1966080)  cvt8(Ws1, Ws1b, i - 1572864);
    else if (i < 2752512)  cvt8(W2,  W2b,  i - 1966080);
    else if (i < 2949120)  cvt8(Ws2, Ws2b, i - 2752512);
}

// -------- gate: logits+softmax+top2, x->bf16, zero out, atomic routing ----------
__global__ __launch_bounds__(256) void k_gate(const float* __restrict__ x,
                                              const float* __restrict__ gw,
                                              unsigned short* __restrict__ xb,
                                              int* __restrict__ tokslot,
                                              float* __restrict__ wroute,
                                              int* __restrict__ cnt,
                                              float* __restrict__ out) {
    const int t = blockIdx.x, tid = threadIdx.x;
    const int lane = tid & 63, w = tid >> 6;
    __shared__ float red[4][8];
    __shared__ float sc[8];

    float4 v = reinterpret_cast<const float4*>(x + (size_t)t * 1024)[tid];
    union { unsigned short u[4]; } o;
    o.u[0]=f2b(v.x); o.u[1]=f2b(v.y); o.u[2]=f2b(v.z); o.u[3]=f2b(v.w);
    reinterpret_cast<ushort4*>(xb + (size_t)t * 1024)[tid] = *(ushort4*)o.u;

    float p[8];
    for (int e = 0; e < 8; e++) {
        float4 g = reinterpret_cast<const float4*>(gw + (size_t)e * 1024)[tid];
        p[e] = v.x*g.x + v.y*g.y + v.z*g.z + v.w*g.w;
    }
    for (int e = 0; e < 8; e++)
        for (int off = 32; off > 0; off >>= 1) p[e] += __shfl_down(p[e], off, 64);
    if (lane == 0)
        for (int e = 0; e < 8; e++) red[w][e] = p[e];
    __syncthreads();
    if (tid < 8) sc[tid] = red[0][tid] + red[1][tid] + red[2][tid] + red[3][tid];
    __syncthreads();
    if (tid == 0) {
        float m = sc[0];
        for (int e = 1; e < 8; e++) m = fmaxf(m, sc[e]);
        float ex[8], sum = 0.f;
        for (int e = 0; e < 8; e++) { ex[e] = expf(sc[e] - m); sum += ex[e]; }
        float inv = 1.f / sum;
        int i1 = 0;
        for (int e = 1; e < 8; e++) if (sc[e] > sc[i1]) i1 = e;
        int i2 = -1; float s2 = -1e30f;
        for (int e = 0; e < 8; e++) if (e != i1 && sc[e] > s2) { s2 = sc[e]; i2 = e; }
        int p1 = atomicAdd(&cnt[i1], 1);
        tokslot[i1 * 2048 + p1] = t; wroute[i1 * 2048 + p1] = ex[i1] * inv;
        int p2 = atomicAdd(&cnt[i2], 1);
        tokslot[i2 * 2048 + p2] = t; wroute[i2 * 2048 + p2] = ex[i2] * inv;
    }
    if (tid == 64) {   // shared pseudo-experts: identity routing
        tokslot[8 * 2048 + t] = t; wroute[8 * 2048 + t] = 1.0f;
        tokslot[9 * 2048 + t] = t; wroute[9 * 2048 + t] = 1.0f;
    }
    reinterpret_cast<float4*>(out + (size_t)t * 1024)[tid] = (float4){0.f, 0.f, 0.f, 0.f};
}

// ---------- unified fc1: 10 experts, M=128 tok x N=64 h-cols, BK=64 ----------
// Grid 864 = 72 mt-slots x 12 ht. 32 MFMA/barrier/wave. LDS 32KB.
__global__ __launch_bounds__(256) void k_fc1u(const unsigned short* __restrict__ xb,
                                              const unsigned short* __restrict__ W1b,
                                              const unsigned short* __restrict__ Ws1b,
                                              const int* __restrict__ tokslot,
                                              const float* __restrict__ wroute,
                                              const int* __restrict__ cnt,
                                              unsigned short* __restrict__ act) {
    __shared__ alignas(16) unsigned short As[128 * 64];   // 16KB
    __shared__ alignas(16) unsigned short Bs[128 * 64];   // 16KB: rows 0..63 y, 64..127 g
    const int tid = threadIdx.x, lane = tid & 63, w = tid >> 6;
    const int wr = w >> 1, wc = w & 1;
    const int mt = blockIdx.x / 12, ht = blockIdx.x % 12;

    int pre = 0, sel = -1, base = 0;
    for (int ee = 0; ee < 10; ee++) {
        int til = (ee < 8) ? ((cnt[ee] + 127) >> 7) : 16;
        if (sel < 0 && mt < pre + til) { sel = ee; base = pre; }
        pre += til;
    }
    if (sel < 0) return;
    const int e = sel, m0 = (mt - base) * 128, h0 = ht * 64;
    const int Te = (e < 8) ? cnt[e] : 2048;
    const unsigned short* Bp = (e < 8) ? (W1b + (size_t)e * 1536 * 1024)
                                       : (Ws1b + (size_t)(e - 8) * 768 * 1024);
    const int gOff = (e < 8) ? 768 : 1536;

    const int kc = tid & 7;
    int aoff[4], boff[4];
    for (int q = 0; q < 4; q++) {
        int row = q * 32 + (tid >> 3);                 // 0..127
        int idx = m0 + row;
        int tk = (idx < Te) ? tokslot[e * 2048 + idx] : 0;
        aoff[q] = tk * 1024 + ((kc ^ (row & 7)) << 3);
        int grow = (row < 64) ? (h0 + row) : (gOff + h0 + row - 64);
        boff[q] = grow * 1024 + ((kc ^ (row & 7)) << 3);
    }

    f32x4 accy[4][2], accg[4][2];
    for (int i = 0; i < 4; i++)
        for (int j = 0; j < 2; j++) {
            accy[i][j] = (f32x4){0.f, 0.f, 0.f, 0.f};
            accg[i][j] = (f32x4){0.f, 0.f, 0.f, 0.f};
        }

    for (int k0 = 0; k0 < 1024; k0 += 64) {
        for (int q = 0; q < 4; q++) {
            ldst16(xb + aoff[q] + k0, As + (q * 256 + tid) * 8);
            ldst16(Bp + boff[q] + k0, Bs + (q * 256 + tid) * 8);
        }
        __syncthreads();
        for (int kh = 0; kh < 2; kh++) {
            const int cq = kh * 4 + (lane >> 4);
            bf16x8 a[4], by[2], bg[2];
            for (int i = 0; i < 4; i++) {
                int r = 64 * wr + 16 * i + (lane & 15);
                a[i] = *(const bf16x8*)&As[r * 64 + ((cq ^ (r & 7)) << 3)];
            }
            for (int j = 0; j < 2; j++) {
                int ry = 32 * wc + 16 * j + (lane & 15);
                by[j] = *(const bf16x8*)&Bs[ry * 64 + ((cq ^ (ry & 7)) << 3)];
                int rg = 64 + ry;
                bg[j] = *(const bf16x8*)&Bs[rg * 64 + ((cq ^ (rg & 7)) << 3)];
            }
            for (int i = 0; i < 4; i++)
                for (int j = 0; j < 2; j++) {
                    accy[i][j] = __builtin_amdgcn_mfma_f32_16x16x32_bf16(a[i], by[j], accy[i][j], 0, 0, 0);
                    accg[i][j] = __builtin_amdgcn_mfma_f32_16x16x32_bf16(a[i], bg[j], accg[i][j], 0, 0, 0);
                }
        }
        __syncthreads();
    }

    for (int i = 0; i < 4; i++)
        for (int r = 0; r < 4; r++) {
            int irow = m0 + 64 * wr + 16 * i + ((lane >> 4) << 2) + r;
            if (irow >= Te) continue;
            float sw = wroute[e * 2048 + irow];
            for (int j = 0; j < 2; j++) {
                float y = accy[i][j][r], g = accg[i][j][r];
                float sg = g / (1.0f + __expf(-g));
                int col = h0 + 32 * wc + 16 * j + (lane & 15);
                act[((size_t)e * 2048 + irow) * 768 + col] = f2b(sw * y * sg);
            }
        }
}

// ---------- unified fc2: 10 experts, M=128 x N=64, BK=128, atomicAdd into out ---------
// Grid 1152 = 72 mt-slots x 16 nt. 32 MFMA/barrier/wave. LDS 48KB.
__global__ __launch_bounds__(256) void k_fc2u(const unsigned short* __restrict__ act,
                                              const unsigned short* __restrict__ W2b,
                                              const unsigned short* __restrict__ Ws2b,
                                              const int* __restrict__ tokslot,
                                              const int* __restrict__ cnt,
                                              float* __restrict__ out) {
    __shared__ alignas(16) unsigned short As[128 * 128];  // 32KB
    __shared__ alignas(16) unsigned short Bs[64 * 128];   // 16KB
    const int tid = threadIdx.x, lane = tid & 63, w = tid >> 6;
    const int wr = w >> 1, wc = w & 1;
    const int mt = blockIdx.x >> 4, nt = blockIdx.x & 15;

    int pre = 0, sel = -1, base = 0;
    for (int ee = 0; ee < 10; ee++) {
        int til = (ee < 8) ? ((cnt[ee] + 127) >> 7) : 16;
        if (sel < 0 && mt < pre + til) { sel = ee; base = pre; }
        pre += til;
    }
    if (sel < 0) return;
    const int e = sel, m0 = (mt - base) * 128, n0 = nt * 64;
    const int Te = (e < 8) ? cnt[e] : 2048;
    const unsigned short* Ab = act + (size_t)e * 2048 * 768;
    const unsigned short* Bb = (e < 8) ? (W2b + (size_t)e * 1024 * 768)
                                       : (Ws2b + (size_t)(e - 8) * 768);
    const int bstride = (e < 8) ? 768 : 1536;

    const int cp = tid & 15;
    int aoff[8], boff[4];
    for (int q = 0; q < 8; q++) {
        int row = q * 16 + (tid >> 4);                 // 0..127
        aoff[q] = (m0 + row) * 768 + ((cp ^ (row & 15)) << 3);
    }
    for (int q = 0; q < 4; q++) {
        int row = q * 16 + (tid >> 4);                 // 0..63
        boff[q] = (n0 + row) * bstride + ((cp ^ (row & 15)) << 3);
    }

    f32x4 acc[4][2];
    for (int i = 0; i < 4; i++)
        for (int j = 0; j < 2; j++) acc[i][j] = (f32x4){0.f, 0.f, 0.f, 0.f};

    for (int k0 = 0; k0 < 768; k0 += 128) {
        for (int q = 0; q < 8; q++) ldst16(Ab + aoff[q] + k0, As + (q * 256 + tid) * 8);
        for (int q = 0; q < 4; q++) ldst16(Bb + boff[q] + k0, Bs + (q * 256 + tid) * 8);
        __syncthreads();
        for (int kh = 0; kh < 4; kh++) {
            const int cq = kh * 4 + (lane >> 4);
            bf16x8 a[4], b[2];
            for (int i = 0; i < 4; i++) {
                int r = 64 * wr + 16 * i + (lane & 15);
                a[i] = *(const bf16x8*)&As[r * 128 + ((cq ^ (r & 15)) << 3)];
            }
            for (int j = 0; j < 2; j++) {
                int rb = 32 * wc + 16 * j + (lane & 15);
                b[j] = *(const bf16x8*)&Bs[rb * 128 + ((cq ^ (rb & 15)) << 3)];
            }
            for (int i = 0; i < 4; i++)
                for (int j = 0; j < 2; j++)
                    acc[i][j] = __builtin_amdgcn_mfma_f32_16x16x32_bf16(a[i], b[j], acc[i][j], 0, 0, 0);
        }
        __syncthreads();
    }

    for (int i = 0; i < 4; i++)
        for (int r = 0; r < 4; r++) {
            int irow = m0 + 64 * wr + 16 * i + ((lane >> 4) << 2) + r;
            if (irow >= Te) continue;
            int t = tokslot[e * 2048 + irow];
            for (int j = 0; j < 2; j++) {
                int col = n0 + 32 * wc + 16 * j + (lane & 15);
                atomicAdd(out + (size_t)t * 1024 + col, acc[i][j][r]);
            }
        }
}

extern "C" void kernel_launch(void* const* d_in, const int* in_sizes, int n_in,
                              void* d_out, int out_size, void* d_ws, size_t ws_size,
                              hipStream_t stream) {
    const float* x   = (const float*)d_in[0];
    const float* gw  = (const float*)d_in[1];
    const float* W1  = (const float*)d_in[2];
    const float* W2  = (const float*)d_in[3];
    const float* Ws1 = (const float*)d_in[4];
    const float* Ws2 = (const float*)d_in[5];
    float* out = (float*)d_out;

    char* ws = (char*)d_ws;
    unsigned short* xb    = (unsigned short*)(ws + 0);          //  4,194,304
    unsigned short* W1b   = (unsigned short*)(ws + 4194304);    // 25,165,824
    unsigned short* Ws1b  = (unsigned short*)(ws + 29360128);   //  6,291,456
    unsigned short* W2b   = (unsigned short*)(ws + 35651584);   // 12,582,912
    unsigned short* Ws2b  = (unsigned short*)(ws + 48234496);   //  3,145,728
    unsigned short* act   = (unsigned short*)(ws + 51380224);   // 31,457,280 (10x2048x768)
    int*            tokslot = (int*)(ws + 82837504);            //     81,920 (10x2048)
    float*          wroute  = (float*)(ws + 82919424);          //     81,920
    int*            cnt     = (int*)(ws + 83001344);            //         64

    k_conv<<<11520, 256, 0, stream>>>(W1, Ws1, W2, Ws2, W1b, Ws1b, W2b, Ws2b, cnt);
    k_gate<<<2048, 256, 0, stream>>>(x, gw, xb, tokslot, wroute, cnt, out);
    k_fc1u<<<864, 256, 0, stream>>>(xb, W1b, Ws1b, tokslot, wroute, cnt, act);
    k_fc2u<<<1152, 256, 0, stream>>>(act, W2b, Ws2b, tokslot, cnt, out);
}

// Round 6
// 276.067 us; speedup vs baseline: 1.0177x; 1.0177x over previous
//
#include <hip/hip_runtime.h>
#include <hip/hip_bf16.h>

// Sparse MoE: T=2048, D=1024, E=8 routed (H=768, top-2) + shared GatedMLP (1536 hidden)
// decomposed into 2 pseudo-experts of routed shape -> 10 uniform experts.
// R6: gate rebuilt with LDS-aggregated routing (64 blocks x 32 tokens, 1 global atomic
// per block-expert instead of per token-expert: R5's 54us atomic tail -> ~6us).
// fc1 M128xN64xBK64 (864 blocks), fc2 M128xN64xBK128 (1152 blocks) unchanged from R5.

typedef short bf16x8 __attribute__((ext_vector_type(8)));
typedef float f32x4 __attribute__((ext_vector_type(4)));

__device__ __forceinline__ unsigned short f2b(float f) {
    __hip_bfloat16 h = __float2bfloat16(f);
    return *reinterpret_cast<unsigned short*>(&h);
}

__device__ __forceinline__ void ldst16(const unsigned short* g, unsigned short* l) {
    __builtin_amdgcn_global_load_lds(
        (const __attribute__((address_space(1))) unsigned int*)g,
        (__attribute__((address_space(3))) unsigned int*)l, 16, 0, 0);
}

__device__ __forceinline__ void cvt8(const float* s, unsigned short* d, int j) {
    const float4* sp = reinterpret_cast<const float4*>(s) + (size_t)j * 2;
    float4 v0 = sp[0], v1 = sp[1];
    union { unsigned short u[8]; uint4 v; } o;
    o.u[0]=f2b(v0.x); o.u[1]=f2b(v0.y); o.u[2]=f2b(v0.z); o.u[3]=f2b(v0.w);
    o.u[4]=f2b(v1.x); o.u[5]=f2b(v1.y); o.u[6]=f2b(v1.z); o.u[7]=f2b(v1.w);
    *(reinterpret_cast<uint4*>(d) + j) = o.v;
}

// ---------------- weight conversion fp32->bf16 (+ zero routing counters) -------------
__global__ __launch_bounds__(256) void k_conv(const float* __restrict__ W1,
                                              const float* __restrict__ Ws1,
                                              const float* __restrict__ W2,
                                              const float* __restrict__ Ws2,
                                              unsigned short* __restrict__ W1b,
                                              unsigned short* __restrict__ Ws1b,
                                              unsigned short* __restrict__ W2b,
                                              unsigned short* __restrict__ Ws2b,
                                              int* __restrict__ cnt) {
    if (blockIdx.x == 0 && threadIdx.x < 16) cnt[threadIdx.x] = 0;
    int i = blockIdx.x * 256 + threadIdx.x;
    if (i < 1572864)       cvt8(W1,  W1b,  i);
    else if (i < 1966080)  cvt8(Ws1, Ws1b, i - 1572864);
    else if (i < 2752512)  cvt8(W2,  W2b,  i - 1966080);
    else if (i < 2949120)  cvt8(Ws2, Ws2b, i - 2752512);
}

// -------- gate: 64 blocks x 32 tokens, 8 lanes/token; LDS-aggregated routing ---------
__global__ __launch_bounds__(256) void k_gate(const float* __restrict__ x,
                                              const float* __restrict__ gw,
                                              unsigned short* __restrict__ xb,
                                              int* __restrict__ tokslot,
                                              float* __restrict__ wroute,
                                              int* __restrict__ cnt,
                                              float* __restrict__ out) {
    const int tid = threadIdx.x;
    const int tloc = tid >> 3;                 // token within block: 0..31
    const int q = tid & 7;                     // k-eighth: 128 floats each
    const int t = blockIdx.x * 32 + tloc;
    __shared__ int lcnt[8];
    __shared__ int gbase[8];
    if (tid < 8) lcnt[tid] = 0;

    const float4* xr = reinterpret_cast<const float4*>(x + (size_t)t * 1024 + q * 128);
    uint4* xbr = reinterpret_cast<uint4*>(xb + (size_t)t * 1024 + q * 128);

    float p[8];
    for (int e = 0; e < 8; e++) p[e] = 0.f;
    float4 buf;
    for (int it = 0; it < 32; it++) {
        float4 v = xr[it];
        for (int e = 0; e < 8; e++) {
            float4 g = reinterpret_cast<const float4*>(gw + (size_t)e * 1024 + q * 128)[it];
            p[e] += v.x*g.x + v.y*g.y + v.z*g.z + v.w*g.w;
        }
        if (it & 1) {
            union { unsigned short u[8]; uint4 uv; } o;
            o.u[0]=f2b(buf.x); o.u[1]=f2b(buf.y); o.u[2]=f2b(buf.z); o.u[3]=f2b(buf.w);
            o.u[4]=f2b(v.x);   o.u[5]=f2b(v.y);   o.u[6]=f2b(v.z);   o.u[7]=f2b(v.w);
            xbr[it >> 1] = o.uv;
        } else buf = v;
    }
    // reduce over the 8 lanes of this token
    for (int e = 0; e < 8; e++) {
        p[e] += __shfl_down(p[e], 4, 64);
        p[e] += __shfl_down(p[e], 2, 64);
        p[e] += __shfl_down(p[e], 1, 64);
    }

    int e1 = 0, e2 = 0, pos1 = 0, pos2 = 0;
    float w1v = 0.f, w2v = 0.f;
    __syncthreads();                           // lcnt zero visible
    if (q == 0) {
        float m = p[0];
        for (int e = 1; e < 8; e++) m = fmaxf(m, p[e]);
        float ex[8], sum = 0.f;
        for (int e = 0; e < 8; e++) { ex[e] = expf(p[e] - m); sum += ex[e]; }
        float inv = 1.f / sum;
        for (int e = 1; e < 8; e++) if (p[e] > p[e1]) e1 = e;
        float s2 = -1e30f; e2 = -1;
        for (int e = 0; e < 8; e++) if (e != e1 && p[e] > s2) { s2 = p[e]; e2 = e; }
        w1v = ex[e1] * inv; w2v = ex[e2] * inv;
        pos1 = atomicAdd(&lcnt[e1], 1);
        pos2 = atomicAdd(&lcnt[e2], 1);
    }
    __syncthreads();
    if (tid < 8) gbase[tid] = atomicAdd(&cnt[tid], lcnt[tid]);
    __syncthreads();
    if (q == 0) {
        int b1 = gbase[e1] + pos1, b2 = gbase[e2] + pos2;
        tokslot[e1 * 2048 + b1] = t; wroute[e1 * 2048 + b1] = w1v;
        tokslot[e2 * 2048 + b2] = t; wroute[e2 * 2048 + b2] = w2v;
        tokslot[8 * 2048 + t] = t;   wroute[8 * 2048 + t] = 1.0f;
        tokslot[9 * 2048 + t] = t;   wroute[9 * 2048 + t] = 1.0f;
    }
    // zero out[t] (this thread's 128-float segment)
    float4 z = (float4){0.f, 0.f, 0.f, 0.f};
    float4* orow = reinterpret_cast<float4*>(out + (size_t)t * 1024 + q * 128);
    for (int it = 0; it < 32; it++) orow[it] = z;
}

// ---------- unified fc1: 10 experts, M=128 tok x N=64 h-cols, BK=64 ----------
// Grid 864 = 72 mt-slots x 12 ht. 32 MFMA/barrier/wave. LDS 32KB.
__global__ __launch_bounds__(256) void k_fc1u(const unsigned short* __restrict__ xb,
                                              const unsigned short* __restrict__ W1b,
                                              const unsigned short* __restrict__ Ws1b,
                                              const int* __restrict__ tokslot,
                                              const float* __restrict__ wroute,
                                              const int* __restrict__ cnt,
                                              unsigned short* __restrict__ act) {
    __shared__ alignas(16) unsigned short As[128 * 64];   // 16KB
    __shared__ alignas(16) unsigned short Bs[128 * 64];   // 16KB: rows 0..63 y, 64..127 g
    const int tid = threadIdx.x, lane = tid & 63, w = tid >> 6;
    const int wr = w >> 1, wc = w & 1;
    const int mt = blockIdx.x / 12, ht = blockIdx.x % 12;

    int pre = 0, sel = -1, base = 0;
    for (int ee = 0; ee < 10; ee++) {
        int til = (ee < 8) ? ((cnt[ee] + 127) >> 7) : 16;
        if (sel < 0 && mt < pre + til) { sel = ee; base = pre; }
        pre += til;
    }
    if (sel < 0) return;
    const int e = sel, m0 = (mt - base) * 128, h0 = ht * 64;
    const int Te = (e < 8) ? cnt[e] : 2048;
    const unsigned short* Bp = (e < 8) ? (W1b + (size_t)e * 1536 * 1024)
                                       : (Ws1b + (size_t)(e - 8) * 768 * 1024);
    const int gOff = (e < 8) ? 768 : 1536;

    const int kc = tid & 7;
    int aoff[4], boff[4];
    for (int q = 0; q < 4; q++) {
        int row = q * 32 + (tid >> 3);                 // 0..127
        int idx = m0 + row;
        int tk = (idx < Te) ? tokslot[e * 2048 + idx] : 0;
        aoff[q] = tk * 1024 + ((kc ^ (row & 7)) << 3);
        int grow = (row < 64) ? (h0 + row) : (gOff + h0 + row - 64);
        boff[q] = grow * 1024 + ((kc ^ (row & 7)) << 3);
    }

    f32x4 accy[4][2], accg[4][2];
    for (int i = 0; i < 4; i++)
        for (int j = 0; j < 2; j++) {
            accy[i][j] = (f32x4){0.f, 0.f, 0.f, 0.f};
            accg[i][j] = (f32x4){0.f, 0.f, 0.f, 0.f};
        }

    for (int k0 = 0; k0 < 1024; k0 += 64) {
        for (int q = 0; q < 4; q++) {
            ldst16(xb + aoff[q] + k0, As + (q * 256 + tid) * 8);
            ldst16(Bp + boff[q] + k0, Bs + (q * 256 + tid) * 8);
        }
        __syncthreads();
        for (int kh = 0; kh < 2; kh++) {
            const int cq = kh * 4 + (lane >> 4);
            bf16x8 a[4], by[2], bg[2];
            for (int i = 0; i < 4; i++) {
                int r = 64 * wr + 16 * i + (lane & 15);
                a[i] = *(const bf16x8*)&As[r * 64 + ((cq ^ (r & 7)) << 3)];
            }
            for (int j = 0; j < 2; j++) {
                int ry = 32 * wc + 16 * j + (lane & 15);
                by[j] = *(const bf16x8*)&Bs[ry * 64 + ((cq ^ (ry & 7)) << 3)];
                int rg = 64 + ry;
                bg[j] = *(const bf16x8*)&Bs[rg * 64 + ((cq ^ (rg & 7)) << 3)];
            }
            for (int i = 0; i < 4; i++)
                for (int j = 0; j < 2; j++) {
                    accy[i][j] = __builtin_amdgcn_mfma_f32_16x16x32_bf16(a[i], by[j], accy[i][j], 0, 0, 0);
                    accg[i][j] = __builtin_amdgcn_mfma_f32_16x16x32_bf16(a[i], bg[j], accg[i][j], 0, 0, 0);
                }
        }
        __syncthreads();
    }

    for (int i = 0; i < 4; i++)
        for (int r = 0; r < 4; r++) {
            int irow = m0 + 64 * wr + 16 * i + ((lane >> 4) << 2) + r;
            if (irow >= Te) continue;
            float sw = wroute[e * 2048 + irow];
            for (int j = 0; j < 2; j++) {
                float y = accy[i][j][r], g = accg[i][j][r];
                float sg = g / (1.0f + __expf(-g));
                int col = h0 + 32 * wc + 16 * j + (lane & 15);
                act[((size_t)e * 2048 + irow) * 768 + col] = f2b(sw * y * sg);
            }
        }
}

// ---------- unified fc2: 10 experts, M=128 x N=64, BK=128, atomicAdd into out ---------
// Grid 1152 = 72 mt-slots x 16 nt. 32 MFMA/barrier/wave. LDS 48KB.
__global__ __launch_bounds__(256) void k_fc2u(const unsigned short* __restrict__ act,
                                              const unsigned short* __restrict__ W2b,
                                              const unsigned short* __restrict__ Ws2b,
                                              const int* __restrict__ tokslot,
                                              const int* __restrict__ cnt,
                                              float* __restrict__ out) {
    __shared__ alignas(16) unsigned short As[128 * 128];  // 32KB
    __shared__ alignas(16) unsigned short Bs[64 * 128];   // 16KB
    const int tid = threadIdx.x, lane = tid & 63, w = tid >> 6;
    const int wr = w >> 1, wc = w & 1;
    const int mt = blockIdx.x >> 4, nt = blockIdx.x & 15;

    int pre = 0, sel = -1, base = 0;
    for (int ee = 0; ee < 10; ee++) {
        int til = (ee < 8) ? ((cnt[ee] + 127) >> 7) : 16;
        if (sel < 0 && mt < pre + til) { sel = ee; base = pre; }
        pre += til;
    }
    if (sel < 0) return;
    const int e = sel, m0 = (mt - base) * 128, n0 = nt * 64;
    const int Te = (e < 8) ? cnt[e] : 2048;
    const unsigned short* Ab = act + (size_t)e * 2048 * 768;
    const unsigned short* Bb = (e < 8) ? (W2b + (size_t)e * 1024 * 768)
                                       : (Ws2b + (size_t)(e - 8) * 768);
    const int bstride = (e < 8) ? 768 : 1536;

    const int cp = tid & 15;
    int aoff[8], boff[4];
    for (int q = 0; q < 8; q++) {
        int row = q * 16 + (tid >> 4);                 // 0..127
        aoff[q] = (m0 + row) * 768 + ((cp ^ (row & 15)) << 3);
    }
    for (int q = 0; q < 4; q++) {
        int row = q * 16 + (tid >> 4);                 // 0..63
        boff[q] = (n0 + row) * bstride + ((cp ^ (row & 15)) << 3);
    }

    f32x4 acc[4][2];
    for (int i = 0; i < 4; i++)
        for (int j = 0; j < 2; j++) acc[i][j] = (f32x4){0.f, 0.f, 0.f, 0.f};

    for (int k0 = 0; k0 < 768; k0 += 128) {
        for (int q = 0; q < 8; q++) ldst16(Ab + aoff[q] + k0, As + (q * 256 + tid) * 8);
        for (int q = 0; q < 4; q++) ldst16(Bb + boff[q] + k0, Bs + (q * 256 + tid) * 8);
        __syncthreads();
        for (int kh = 0; kh < 4; kh++) {
            const int cq = kh * 4 + (lane >> 4);
            bf16x8 a[4], b[2];
            for (int i = 0; i < 4; i++) {
                int r = 64 * wr + 16 * i + (lane & 15);
                a[i] = *(const bf16x8*)&As[r * 128 + ((cq ^ (r & 15)) << 3)];
            }
            for (int j = 0; j < 2; j++) {
                int rb = 32 * wc + 16 * j + (lane & 15);
                b[j] = *(const bf16x8*)&Bs[rb * 128 + ((cq ^ (rb & 15)) << 3)];
            }
            for (int i = 0; i < 4; i++)
                for (int j = 0; j < 2; j++)
                    acc[i][j] = __builtin_amdgcn_mfma_f32_16x16x32_bf16(a[i], b[j], acc[i][j], 0, 0, 0);
        }
        __syncthreads();
    }

    for (int i = 0; i < 4; i++)
        for (int r = 0; r < 4; r++) {
            int irow = m0 + 64 * wr + 16 * i + ((lane >> 4) << 2) + r;
            if (irow >= Te) continue;
            int t = tokslot[e * 2048 + irow];
            for (int j = 0; j < 2; j++) {
                int col = n0 + 32 * wc + 16 * j + (lane & 15);
                atomicAdd(out + (size_t)t * 1024 + col, acc[i][j][r]);
            }
        }
}

extern "C" void kernel_launch(void* const* d_in, const int* in_sizes, int n_in,
                              void* d_out, int out_size, void* d_ws, size_t ws_size,
                              hipStream_t stream) {
    const float* x   = (const float*)d_in[0];
    const float* gw  = (const float*)d_in[1];
    const float* W1  = (const float*)d_in[2];
    const float* W2  = (const float*)d_in[3];
    const float* Ws1 = (const float*)d_in[4];
    const float* Ws2 = (const float*)d_in[5];
    float* out = (float*)d_out;

    char* ws = (char*)d_ws;
    unsigned short* xb    = (unsigned short*)(ws + 0);          //  4,194,304
    unsigned short* W1b   = (unsigned short*)(ws + 4194304);    // 25,165,824
    unsigned short* Ws1b  = (unsigned short*)(ws + 29360128);   //  6,291,456
    unsigned short* W2b   = (unsigned short*)(ws + 35651584);   // 12,582,912
    unsigned short* Ws2b  = (unsigned short*)(ws + 48234496);   //  3,145,728
    unsigned short* act   = (unsigned short*)(ws + 51380224);   // 31,457,280 (10x2048x768)
    int*            tokslot = (int*)(ws + 82837504);            //     81,920 (10x2048)
    float*          wroute  = (float*)(ws + 82919424);          //     81,920
    int*            cnt     = (int*)(ws + 83001344);            //         64

    k_conv<<<11520, 256, 0, stream>>>(W1, Ws1, W2, Ws2, W1b, Ws1b, W2b, Ws2b, cnt);
    k_gate<<<64, 256, 0, stream>>>(x, gw, xb, tokslot, wroute, cnt, out);
    k_fc1u<<<864, 256, 0, stream>>>(xb, W1b, Ws1b, tokslot, wroute, cnt, act);
    k_fc2u<<<1152, 256, 0, stream>>>(act, W2b, Ws2b, tokslot, cnt, out);
}

// Round 7
// 235.080 us; speedup vs baseline: 1.1951x; 1.1744x over previous
//
#include <hip/hip_runtime.h>
#include <hip/hip_bf16.h>

// Sparse MoE: T=2048, D=1024, E=8 routed (H=768, top-2) + shared GatedMLP (1536 hidden).
// R7: 3 kernels. conv+gate merged (gate = coalesced per-token blocks, padded-counter
// atomics); fc1 10 uniform experts M128xN64xBK64; fc2 single kernel (routed K=768 tiles
// + shared K=1536 tiles), atomicAdd into out zeroed by gate.

typedef short bf16x8 __attribute__((ext_vector_type(8)));
typedef float f32x4 __attribute__((ext_vector_type(4)));

__device__ __forceinline__ unsigned short f2b(float f) {
    __hip_bfloat16 h = __float2bfloat16(f);
    return *reinterpret_cast<unsigned short*>(&h);
}

__device__ __forceinline__ void ldst16(const unsigned short* g, unsigned short* l) {
    __builtin_amdgcn_global_load_lds(
        (const __attribute__((address_space(1))) unsigned int*)g,
        (__attribute__((address_space(3))) unsigned int*)l, 16, 0, 0);
}

__device__ __forceinline__ void cvt8(const float* s, unsigned short* d, int j) {
    const float4* sp = reinterpret_cast<const float4*>(s) + (size_t)j * 2;
    float4 v0 = sp[0], v1 = sp[1];
    union { unsigned short u[8]; uint4 v; } o;
    o.u[0]=f2b(v0.x); o.u[1]=f2b(v0.y); o.u[2]=f2b(v0.z); o.u[3]=f2b(v0.w);
    o.u[4]=f2b(v1.x); o.u[5]=f2b(v1.y); o.u[6]=f2b(v1.z); o.u[7]=f2b(v1.w);
    *(reinterpret_cast<uint4*>(d) + j) = o.v;
}

// ------- merged: weight conversion (blocks 0..11519) + gate (blocks 11520..13567) -----
__global__ __launch_bounds__(256) void k_convgate(const float* __restrict__ x,
                                                  const float* __restrict__ gw,
                                                  const float* __restrict__ W1,
                                                  const float* __restrict__ Ws1,
                                                  const float* __restrict__ W2,
                                                  const float* __restrict__ Ws2,
                                                  unsigned short* __restrict__ xb,
                                                  unsigned short* __restrict__ W1b,
                                                  unsigned short* __restrict__ Ws1b,
                                                  unsigned short* __restrict__ W2b,
                                                  unsigned short* __restrict__ Ws2b,
                                                  int* __restrict__ tokslot,
                                                  float* __restrict__ wroute,
                                                  int* __restrict__ cnt,
                                                  float* __restrict__ out) {
    __shared__ float red[4][8];
    __shared__ float sc[8];
    const int b = blockIdx.x, tid = threadIdx.x;
    if (b < 11520) {
        int i = b * 256 + tid;
        if (i < 1572864)       cvt8(W1,  W1b,  i);
        else if (i < 1966080)  cvt8(Ws1, Ws1b, i - 1572864);
        else if (i < 2752512)  cvt8(W2,  W2b,  i - 1966080);
        else if (i < 2949120)  cvt8(Ws2, Ws2b, i - 2752512);
        return;
    }
    // ---- gate: one token per block, fully coalesced ----
    const int t = b - 11520;
    const int lane = tid & 63, w = tid >> 6;

    float4 v = reinterpret_cast<const float4*>(x + (size_t)t * 1024)[tid];
    union { unsigned short u[4]; } o;
    o.u[0]=f2b(v.x); o.u[1]=f2b(v.y); o.u[2]=f2b(v.z); o.u[3]=f2b(v.w);
    reinterpret_cast<ushort4*>(xb + (size_t)t * 1024)[tid] = *(ushort4*)o.u;

    float p[8];
    for (int e = 0; e < 8; e++) {
        float4 g = reinterpret_cast<const float4*>(gw + (size_t)e * 1024)[tid];
        p[e] = v.x*g.x + v.y*g.y + v.z*g.z + v.w*g.w;
    }
    for (int e = 0; e < 8; e++)
        for (int off = 32; off > 0; off >>= 1) p[e] += __shfl_down(p[e], off, 64);
    if (lane == 0)
        for (int e = 0; e < 8; e++) red[w][e] = p[e];
    __syncthreads();
    if (tid < 8) sc[tid] = red[0][tid] + red[1][tid] + red[2][tid] + red[3][tid];
    __syncthreads();
    if (tid == 0) {
        float m = sc[0];
        for (int e = 1; e < 8; e++) m = fmaxf(m, sc[e]);
        float ex[8], sum = 0.f;
        for (int e = 0; e < 8; e++) { ex[e] = expf(sc[e] - m); sum += ex[e]; }
        float inv = 1.f / sum;
        int i1 = 0;
        for (int e = 1; e < 8; e++) if (sc[e] > sc[i1]) i1 = e;
        int i2 = -1; float s2 = -1e30f;
        for (int e = 0; e < 8; e++) if (e != i1 && sc[e] > s2) { s2 = sc[e]; i2 = e; }
        int p1 = atomicAdd(&cnt[i1 * 16], 1);          // 64B-padded counters
        tokslot[i1 * 2048 + p1] = t; wroute[i1 * 2048 + p1] = ex[i1] * inv;
        int p2 = atomicAdd(&cnt[i2 * 16], 1);
        tokslot[i2 * 2048 + p2] = t; wroute[i2 * 2048 + p2] = ex[i2] * inv;
    }
    reinterpret_cast<float4*>(out + (size_t)t * 1024)[tid] = (float4){0.f, 0.f, 0.f, 0.f};
}

// ---------- unified fc1: 10 experts (8 routed + 2 shared pseudo), M128 x N64, BK=64 ---
// Grid 864 = 72 mt-slots x 12 ht. Pseudo-experts: identity routing, output token-major.
__global__ __launch_bounds__(256) void k_fc1u(const unsigned short* __restrict__ xb,
                                              const unsigned short* __restrict__ W1b,
                                              const unsigned short* __restrict__ Ws1b,
                                              const int* __restrict__ tokslot,
                                              const float* __restrict__ wroute,
                                              const int* __restrict__ cnt,
                                              unsigned short* __restrict__ act_r,
                                              unsigned short* __restrict__ acts) {
    __shared__ alignas(16) unsigned short As[128 * 64];   // 16KB
    __shared__ alignas(16) unsigned short Bs[128 * 64];   // 16KB: rows 0..63 y, 64..127 g
    const int tid = threadIdx.x, lane = tid & 63, w = tid >> 6;
    const int wr = w >> 1, wc = w & 1;
    const int mt = blockIdx.x / 12, ht = blockIdx.x % 12;

    int pre = 0, sel = -1, base = 0;
    for (int ee = 0; ee < 10; ee++) {
        int til = (ee < 8) ? ((cnt[ee * 16] + 127) >> 7) : 16;
        if (sel < 0 && mt < pre + til) { sel = ee; base = pre; }
        pre += til;
    }
    if (sel < 0) return;
    const int e = sel, m0 = (mt - base) * 128, h0 = ht * 64;
    const int Te = (e < 8) ? cnt[e * 16] : 2048;
    const unsigned short* Bp = (e < 8) ? (W1b + (size_t)e * 1536 * 1024)
                                       : (Ws1b + (size_t)(e - 8) * 768 * 1024);
    const int gOff = (e < 8) ? 768 : 1536;

    const int kc = tid & 7;
    int aoff[4], boff[4];
    for (int q = 0; q < 4; q++) {
        int row = q * 32 + (tid >> 3);                 // 0..127
        int idx = m0 + row;
        int tk = (e < 8) ? ((idx < Te) ? tokslot[e * 2048 + idx] : 0) : idx;
        aoff[q] = tk * 1024 + ((kc ^ (row & 7)) << 3);
        int grow = (row < 64) ? (h0 + row) : (gOff + h0 + row - 64);
        boff[q] = grow * 1024 + ((kc ^ (row & 7)) << 3);
    }

    f32x4 accy[4][2], accg[4][2];
    for (int i = 0; i < 4; i++)
        for (int j = 0; j < 2; j++) {
            accy[i][j] = (f32x4){0.f, 0.f, 0.f, 0.f};
            accg[i][j] = (f32x4){0.f, 0.f, 0.f, 0.f};
        }

    for (int k0 = 0; k0 < 1024; k0 += 64) {
        for (int q = 0; q < 4; q++) {
            ldst16(xb + aoff[q] + k0, As + (q * 256 + tid) * 8);
            ldst16(Bp + boff[q] + k0, Bs + (q * 256 + tid) * 8);
        }
        __syncthreads();
        for (int kh = 0; kh < 2; kh++) {
            const int cq = kh * 4 + (lane >> 4);
            bf16x8 a[4], by[2], bg[2];
            for (int i = 0; i < 4; i++) {
                int r = 64 * wr + 16 * i + (lane & 15);
                a[i] = *(const bf16x8*)&As[r * 64 + ((cq ^ (r & 7)) << 3)];
            }
            for (int j = 0; j < 2; j++) {
                int ry = 32 * wc + 16 * j + (lane & 15);
                by[j] = *(const bf16x8*)&Bs[ry * 64 + ((cq ^ (ry & 7)) << 3)];
                int rg = 64 + ry;
                bg[j] = *(const bf16x8*)&Bs[rg * 64 + ((cq ^ (rg & 7)) << 3)];
            }
            for (int i = 0; i < 4; i++)
                for (int j = 0; j < 2; j++) {
                    accy[i][j] = __builtin_amdgcn_mfma_f32_16x16x32_bf16(a[i], by[j], accy[i][j], 0, 0, 0);
                    accg[i][j] = __builtin_amdgcn_mfma_f32_16x16x32_bf16(a[i], bg[j], accg[i][j], 0, 0, 0);
                }
        }
        __syncthreads();
    }

    for (int i = 0; i < 4; i++)
        for (int r = 0; r < 4; r++) {
            int irow = m0 + 64 * wr + 16 * i + ((lane >> 4) << 2) + r;
            if (irow >= Te) continue;
            float sw = (e < 8) ? wroute[e * 2048 + irow] : 1.0f;
            unsigned short* dst = (e < 8)
                ? (act_r + ((size_t)e * 2048 + irow) * 768)
                : (acts + (size_t)irow * 1536 + (size_t)(e - 8) * 768);
            for (int j = 0; j < 2; j++) {
                float y = accy[i][j][r], g = accg[i][j][r];
                float sg = g / (1.0f + __expf(-g));
                int col = h0 + 32 * wc + 16 * j + (lane & 15);
                dst[col] = f2b(sw * y * sg);
            }
        }
}

// ------- unified fc2: routed (K=768) + shared (K=1536) tiles, atomicAdd into out ------
// M=128 x N=64, BK=128. Grid 896 = 56 mt-slots x 16 nt. LDS 48KB.
__global__ __launch_bounds__(256) void k_fc2u(const unsigned short* __restrict__ act_r,
                                              const unsigned short* __restrict__ acts,
                                              const unsigned short* __restrict__ W2b,
                                              const unsigned short* __restrict__ Ws2b,
                                              const int* __restrict__ tokslot,
                                              const int* __restrict__ cnt,
                                              float* __restrict__ out) {
    __shared__ alignas(16) unsigned short As[128 * 128];  // 32KB
    __shared__ alignas(16) unsigned short Bs[64 * 128];   // 16KB
    const int tid = threadIdx.x, lane = tid & 63, w = tid >> 6;
    const int wr = w >> 1, wc = w & 1;
    const int mt = blockIdx.x >> 4, nt = blockIdx.x & 15;

    int pre = 0, sel = -1, base = 0;
    for (int ee = 0; ee < 9; ee++) {
        int til = (ee < 8) ? ((cnt[ee * 16] + 127) >> 7) : 16;
        if (sel < 0 && mt < pre + til) { sel = ee; base = pre; }
        pre += til;
    }
    if (sel < 0) return;
    const int e = sel, m0 = (mt - base) * 128, n0 = nt * 64;
    int Te, astride, bstride, K;
    const unsigned short *Ab, *Bb;
    if (e < 8) {
        Te = cnt[e * 16]; K = 768; astride = 768; bstride = 768;
        Ab = act_r + (size_t)e * 2048 * 768;
        Bb = W2b + (size_t)e * 1024 * 768;
    } else {
        Te = 2048; K = 1536; astride = 1536; bstride = 1536;
        Ab = acts;
        Bb = Ws2b;
    }

    const int cp = tid & 15;
    int aoff[8], boff[4];
    for (int q = 0; q < 8; q++) {
        int row = q * 16 + (tid >> 4);                 // 0..127
        aoff[q] = (m0 + row) * astride + ((cp ^ (row & 15)) << 3);
    }
    for (int q = 0; q < 4; q++) {
        int row = q * 16 + (tid >> 4);                 // 0..63
        boff[q] = (n0 + row) * bstride + ((cp ^ (row & 15)) << 3);
    }

    f32x4 acc[4][2];
    for (int i = 0; i < 4; i++)
        for (int j = 0; j < 2; j++) acc[i][j] = (f32x4){0.f, 0.f, 0.f, 0.f};

    for (int k0 = 0; k0 < K; k0 += 128) {
        for (int q = 0; q < 8; q++) ldst16(Ab + aoff[q] + k0, As + (q * 256 + tid) * 8);
        for (int q = 0; q < 4; q++) ldst16(Bb + boff[q] + k0, Bs + (q * 256 + tid) * 8);
        __syncthreads();
        for (int kh = 0; kh < 4; kh++) {
            const int cq = kh * 4 + (lane >> 4);
            bf16x8 a[4], b[2];
            for (int i = 0; i < 4; i++) {
                int r = 64 * wr + 16 * i + (lane & 15);
                a[i] = *(const bf16x8*)&As[r * 128 + ((cq ^ (r & 15)) << 3)];
            }
            for (int j = 0; j < 2; j++) {
                int rb = 32 * wc + 16 * j + (lane & 15);
                b[j] = *(const bf16x8*)&Bs[rb * 128 + ((cq ^ (rb & 15)) << 3)];
            }
            for (int i = 0; i < 4; i++)
                for (int j = 0; j < 2; j++)
                    acc[i][j] = __builtin_amdgcn_mfma_f32_16x16x32_bf16(a[i], b[j], acc[i][j], 0, 0, 0);
        }
        __syncthreads();
    }

    for (int i = 0; i < 4; i++)
        for (int r = 0; r < 4; r++) {
            int irow = m0 + 64 * wr + 16 * i + ((lane >> 4) << 2) + r;
            if (irow >= Te) continue;
            int t = (e < 8) ? tokslot[e * 2048 + irow] : irow;
            for (int j = 0; j < 2; j++) {
                int col = n0 + 32 * wc + 16 * j + (lane & 15);
                atomicAdd(out + (size_t)t * 1024 + col, acc[i][j][r]);
            }
        }
}

extern "C" void kernel_launch(void* const* d_in, const int* in_sizes, int n_in,
                              void* d_out, int out_size, void* d_ws, size_t ws_size,
                              hipStream_t stream) {
    const float* x   = (const float*)d_in[0];
    const float* gw  = (const float*)d_in[1];
    const float* W1  = (const float*)d_in[2];
    const float* W2  = (const float*)d_in[3];
    const float* Ws1 = (const float*)d_in[4];
    const float* Ws2 = (const float*)d_in[5];
    float* out = (float*)d_out;

    char* ws = (char*)d_ws;
    unsigned short* xb    = (unsigned short*)(ws + 0);          //  4,194,304
    unsigned short* W1b   = (unsigned short*)(ws + 4194304);    // 25,165,824
    unsigned short* Ws1b  = (unsigned short*)(ws + 29360128);   //  6,291,456
    unsigned short* W2b   = (unsigned short*)(ws + 35651584);   // 12,582,912
    unsigned short* Ws2b  = (unsigned short*)(ws + 48234496);   //  3,145,728
    unsigned short* act_r = (unsigned short*)(ws + 51380224);   // 25,165,824 (8x2048x768)
    unsigned short* acts  = (unsigned short*)(ws + 76546048);   //  6,291,456 (2048x1536)
    int*            tokslot = (int*)(ws + 82837504);            //     65,536 (8x2048)
    float*          wroute  = (float*)(ws + 82903040);          //     65,536
    int*            cnt     = (int*)(ws + 82968576);            //        512 (8x16 ints)

    hipMemsetAsync(cnt, 0, 512, stream);
    k_convgate<<<13568, 256, 0, stream>>>(x, gw, W1, Ws1, W2, Ws2,
                                          xb, W1b, Ws1b, W2b, Ws2b,
                                          tokslot, wroute, cnt, out);
    k_fc1u<<<864, 256, 0, stream>>>(xb, W1b, Ws1b, tokslot, wroute, cnt, act_r, acts);
    k_fc2u<<<896, 256, 0, stream>>>(act_r, acts, W2b, Ws2b, tokslot, cnt, out);
}